// Round 3
// baseline (299.480 us; speedup 1.0000x reference)
//
#include <hip/hip_runtime.h>
#include <hip/hip_bf16.h>

#define N_NODES 102

typedef _Float16 f16x8 __attribute__((ext_vector_type(8)));
typedef _Float16 f16x2 __attribute__((ext_vector_type(2)));
typedef float f32x4 __attribute__((ext_vector_type(4)));

#define LDW 264  // padded LDS row stride in f16 elems (264*2B = 528B, odd 16B units)

// ---------------- Kernel 1: build normalized adjacency (exactly per reference) ---
__global__ void build_adj(const int* __restrict__ ei, int ne, float* __restrict__ A) {
    __shared__ int deg[N_NODES];
    __shared__ float dinv[N_NODES];
    int t = threadIdx.x;
    if (t < N_NODES) deg[t] = 1;  // self-loop
    __syncthreads();
    if (t == 0) {
        for (int e = 0; e < ne; ++e) deg[ei[ne + e]] += 1;  // deg over col index
    }
    __syncthreads();
    if (t < N_NODES) dinv[t] = 1.0f / sqrtf((float)deg[t]);
    __syncthreads();
    for (int i = t; i < N_NODES * N_NODES; i += blockDim.x) A[i] = 0.0f;
    __syncthreads();
    if (t == 0) {
        for (int e = 0; e < ne; ++e) {
            int r = ei[e], c = ei[ne + e];
            A[c * N_NODES + r] += dinv[r] * dinv[c];   // out[col] += norm * x[row]
        }
    }
    __syncthreads();
    if (t < N_NODES) A[t * N_NODES + t] += dinv[t] * dinv[t];  // diagonal self-loops
}

// ---------------- Kernel 2: y[p][v][c] = sum_u A[v,u] * xf[p,u,c] ----------------
__global__ void compute_y(const float* __restrict__ x,
                          const float* __restrict__ A,
                          float* __restrict__ y) {
    int p = blockIdx.x;
    __shared__ float xs[N_NODES * 2];
    int t = threadIdx.x;
    const float* xp = x + (size_t)p * (N_NODES * 2);
    for (int i = t; i < N_NODES * 2; i += 128) xs[i] = xp[i];
    __syncthreads();
    if (t < N_NODES) {
        float a0 = 0.0f, a1 = 0.0f;
        const float* Arow = A + t * N_NODES;
        for (int u = 0; u < N_NODES; ++u) {
            float a = Arow[u];
            a0 += a * xs[2 * u];
            a1 += a * xs[2 * u + 1];
        }
        size_t r = (size_t)p * N_NODES + t;
        y[r * 2]     = a0;
        y[r * 2 + 1] = a1;
    }
}

// ---------------- Kernel 3: out[r][e] = relu(y0*W0 + y1*W1 + b) @ Wp + bp --------
// Block: 256 threads = 4 waves. Block tile: 256 rows x 64 cols (wave: 64 rows x 64 cols).
// A-operand (h) generated in-register from y + W slices; B-operand (W_proj^T slice) in LDS.
__global__ __launch_bounds__(256, 2) void gnn_main(
    const float* __restrict__ y,     // [R][2] fp32
    const float* __restrict__ Wg,    // [2][256]
    const float* __restrict__ bg,    // [256]
    const float* __restrict__ Wp,    // [256][256] (k-major)
    const float* __restrict__ bp,    // [256]
    float* __restrict__ out)         // [R][256]
{
    __shared__ _Float16 Wl[64 * LDW];
    const int tid = threadIdx.x;
    const int c0 = blockIdx.y * 64;

    // Stage W_proj[:, c0:c0+64] transposed -> Wl[cc][k] as f16
    {
        int cc = tid & 63;
        int ks = tid >> 6;
        for (int k = ks; k < 256; k += 4) {
            Wl[cc * LDW + k] = (_Float16)Wp[k * 256 + c0 + cc];
        }
    }
    __syncthreads();

    const int w  = tid >> 6;   // wave 0..3
    const int l  = tid & 63;   // lane
    const int qk = l >> 4;     // k-quarter 0..3
    const int m  = l & 15;

    // Per-lane slices of W0/W1/b as packed f16x2: k = qk*8 + 32*t + 2*j2 + {0,1}
    f16x2 w0pk[8][4], w1pk[8][4], bpk[8][4];
    #pragma unroll
    for (int t = 0; t < 8; ++t) {
        int k0 = qk * 8 + 32 * t;
        #pragma unroll
        for (int j2 = 0; j2 < 4; ++j2) {
            w0pk[t][j2] = (f16x2){ (_Float16)Wg[k0 + 2 * j2],
                                   (_Float16)Wg[k0 + 2 * j2 + 1] };
            w1pk[t][j2] = (f16x2){ (_Float16)Wg[256 + k0 + 2 * j2],
                                   (_Float16)Wg[256 + k0 + 2 * j2 + 1] };
            bpk[t][j2]  = (f16x2){ (_Float16)bg[k0 + 2 * j2],
                                   (_Float16)bg[k0 + 2 * j2 + 1] };
        }
    }

    const long rowbase = (long)blockIdx.x * 256 + (long)w * 64;

    // y per row-stripe (A-frag row = lane&15)
    f16x2 y0pk[4], y1pk[4];
    #pragma unroll
    for (int s = 0; s < 4; ++s) {
        long r = rowbase + s * 16 + m;
        float2 yv = *reinterpret_cast<const float2*>(&y[r * 2]);
        _Float16 h0 = (_Float16)yv.x;
        _Float16 h1 = (_Float16)yv.y;
        y0pk[s] = (f16x2){ h0, h0 };
        y1pk[s] = (f16x2){ h1, h1 };
    }

    f32x4 acc[4][4];
    #pragma unroll
    for (int s = 0; s < 4; ++s)
        #pragma unroll
        for (int nt = 0; nt < 4; ++nt)
            acc[s][nt] = (f32x4){0.f, 0.f, 0.f, 0.f};

    const f16x2 z2 = (f16x2){ (_Float16)0.0f, (_Float16)0.0f };

    #pragma unroll
    for (int t = 0; t < 8; ++t) {
        const int kk = qk * 8 + 32 * t;
        f16x8 bfrag[4];
        #pragma unroll
        for (int nt = 0; nt < 4; ++nt)
            bfrag[nt] = *reinterpret_cast<const f16x8*>(&Wl[(nt * 16 + m) * LDW + kk]);
        #pragma unroll
        for (int s = 0; s < 4; ++s) {
            union { f16x8 v; f16x2 p[4]; } af;
            #pragma unroll
            for (int j2 = 0; j2 < 4; ++j2) {
                f16x2 h = w0pk[t][j2] * y0pk[s] + w1pk[t][j2] * y1pk[s] + bpk[t][j2];
                af.p[j2] = __builtin_elementwise_max(h, z2);
            }
            #pragma unroll
            for (int nt = 0; nt < 4; ++nt)
                acc[s][nt] = __builtin_amdgcn_mfma_f32_16x16x32_f16(af.v, bfrag[nt], acc[s][nt], 0, 0, 0);
        }
    }

    // Epilogue: + b_proj, store fp32
    float bpf[4];
    #pragma unroll
    for (int nt = 0; nt < 4; ++nt) bpf[nt] = bp[c0 + nt * 16 + m];
    #pragma unroll
    for (int s = 0; s < 4; ++s) {
        #pragma unroll
        for (int nt = 0; nt < 4; ++nt) {
            const int e = c0 + nt * 16 + m;
            #pragma unroll
            for (int reg = 0; reg < 4; ++reg) {
                long r = rowbase + s * 16 + qk * 4 + reg;
                out[r * 256 + e] = acc[s][nt][reg] + bpf[nt];
            }
        }
    }
}

extern "C" void kernel_launch(void* const* d_in, const int* in_sizes, int n_in,
                              void* d_out, int out_size, void* d_ws, size_t ws_size,
                              hipStream_t stream) {
    const float* x  = (const float*)d_in[0];
    const float* Wg = (const float*)d_in[1];
    const float* bg = (const float*)d_in[2];
    const float* Wp = (const float*)d_in[3];
    const float* bp = (const float*)d_in[4];
    const int* ei   = (const int*)d_in[5];
    float* out = (float*)d_out;

    const int ne    = in_sizes[5] / 2;              // 84
    const int pairs = in_sizes[0] / (N_NODES * 2);  // 8192

    float* yws = (float*)d_ws;
    float* A   = (float*)((char*)d_ws + (size_t)pairs * N_NODES * 2 * sizeof(float));

    build_adj<<<1, 128, 0, stream>>>(ei, ne, A);
    compute_y<<<pairs, 128, 0, stream>>>(x, A, yws);

    const int rowblocks = pairs * N_NODES / 256;    // 3264
    gnn_main<<<dim3(rowblocks, 4), 256, 0, stream>>>(yws, Wg, bg, Wp, bp, out);
}